// Round 17
// baseline (817.214 us; speedup 1.0000x reference)
//
#include <hip/hip_runtime.h>
#include <hip/hip_bf16.h>
#include <hip/hip_fp16.h>

#define B_    8192
#define D_    1024
#define H_    4096
#define DOUT_ 1024
#define E_    8
#define MAXR  17408   // 16384 assignments + 8*128 padding

typedef float    f32x4 __attribute__((ext_vector_type(4)));
typedef _Float16 f16x8 __attribute__((ext_vector_type(8)));
typedef unsigned short u16;
typedef u16      u16x8 __attribute__((ext_vector_type(8)));
typedef u16      u16x4 __attribute__((ext_vector_type(4)));
typedef unsigned int u32;

__device__ __forceinline__ u16 f2h_bits(float f) {
  _Float16 h = (_Float16)f;
  return __builtin_bit_cast(u16, h);
}
__device__ __forceinline__ float h2f(u16 b) {
  return (float)__builtin_bit_cast(_Float16, b);
}

// tanh-form gelu (max abs err vs erf-gelu ~3e-4; threshold margin 4x)
__device__ __forceinline__ float gelu_f(float v) {
  float z = 0.7978845608028654f * (v + 0.044715f * v * v * v);
  float ez = __expf(2.f * z);
  float th = 1.f - 2.f / (ez + 1.f);
  return 0.5f * v * (1.f + th);
}

// ---- workspace layout (bytes) ----
#define OFF_TOPI 512                       // int[16384]
#define OFF_TOPW (OFF_TOPI + 65536)        // float[16384]
#define OFF_ATOK (OFF_TOPW + 65536)        // int[17408]
#define OFF_SLOT (OFF_ATOK + 69632)        // int[16384] slot_of
#define OFF_XG   524288                    // u16[17408*1024] f16 (dead after gemm1)
#define OFF_W1T  (OFF_XG + 35651584)       // u16[8*4096*1024] f16 (dead after gemm1)
#define OFF_W2T  OFF_XG                    // u16[8*1024*4096], ALIASES Xg (built after gemm1)
#define OFF_Y    (OFF_XG + 67108864)       // u16[17408*1024], ALIASES W1T tail (after gemm1)
#define OFF_HB   (OFF_W1T + 67108864)      // u16[17408*4096] f16
// end = 245,891,072 bytes

__global__ void k_init(int* __restrict__ atok, int* __restrict__ meta) {
  int i = blockIdx.x * 256 + threadIdx.x;
  if (i < MAXR) atok[i] = 0;
  if (blockIdx.x == 0 && threadIdx.x < 64) meta[threadIdx.x] = 0;
}

__global__ __launch_bounds__(256) void k_gate(
    const float* __restrict__ x, const float* __restrict__ Wg,
    const float* __restrict__ bg, int* __restrict__ counts,
    float* __restrict__ usage, int* __restrict__ topi, float* __restrict__ topw) {
  __shared__ float su[E_];
  if (threadIdx.x < E_) su[threadIdx.x] = 0.f;
  __syncthreads();
  const int lane = threadIdx.x & 63;
  const int b = blockIdx.x * 4 + (threadIdx.x >> 6);
  float p[E_] = {0.f,0.f,0.f,0.f,0.f,0.f,0.f,0.f};
  #pragma unroll
  for (int j = 0; j < 4; ++j) {
    int d = j * 256 + lane * 4;
    float4 xv = *(const float4*)&x[(size_t)b * D_ + d];
    const float* wr = &Wg[(size_t)d * E_];
    #pragma unroll
    for (int c = 0; c < 4; ++c) {
      float xc = reinterpret_cast<const float*>(&xv)[c];
      #pragma unroll
      for (int e = 0; e < E_; ++e) p[e] += xc * wr[c * E_ + e];
    }
  }
  #pragma unroll
  for (int off = 32; off >= 1; off >>= 1)
    #pragma unroll
    for (int e = 0; e < E_; ++e) p[e] += __shfl_xor(p[e], off, 64);
  float mx = -1e30f;
  #pragma unroll
  for (int e = 0; e < E_; ++e) { p[e] += bg[e]; mx = fmaxf(mx, p[e]); }
  int i0 = 0; float l0 = p[0];
  #pragma unroll
  for (int e = 1; e < E_; ++e) if (p[e] > l0) { l0 = p[e]; i0 = e; }
  int i1 = -1; float l1 = -1e30f;
  #pragma unroll
  for (int e = 0; e < E_; ++e) if (e != i0 && p[e] > l1) { l1 = p[e]; i1 = e; }
  float s = 0.f;
  #pragma unroll
  for (int e = 0; e < E_; ++e) { p[e] = expf(p[e] - mx); s += p[e]; }
  float inv = 1.f / s;
  if (lane == 0) {
    float e0 = expf(l0 - mx), e1 = expf(l1 - mx);
    float wsum = e0 + e1;
    topi[b * 2] = i0; topi[b * 2 + 1] = i1;
    topw[b * 2] = e0 / wsum; topw[b * 2 + 1] = e1 / wsum;
    atomicAdd(&counts[i0], 1);
    atomicAdd(&counts[i1], 1);
    #pragma unroll
    for (int e = 0; e < E_; ++e) atomicAdd(&su[e], p[e] * inv);
  }
  __syncthreads();
  if (threadIdx.x < E_) atomicAdd(&usage[threadIdx.x], su[threadIdx.x]);
}

__global__ void k_scan_aux(const int* __restrict__ counts, int* __restrict__ offsets,
                           const float* __restrict__ usage, float* __restrict__ auxp) {
  if (threadIdx.x == 0) {
    int off = 0;
    for (int e = 0; e < E_; ++e) { offsets[e] = off; off += (counts[e] + 127) & ~127; }
    offsets[E_] = off;
    float aux = 0.f;
    const float lu = logf(1.0f / (float)E_);
    for (int e = 0; e < E_; ++e) {
      float u = usage[e] * (1.0f / (float)B_);
      aux += u * lu - logf(u) * (1.0f / (float)E_);
    }
    *auxp = aux;
  }
}

__global__ void k_scatter(const int* __restrict__ topi, const int* __restrict__ offsets,
                          int* __restrict__ cursors, int* __restrict__ atok,
                          int* __restrict__ slot_of) {
  int b = blockIdx.x * 256 + threadIdx.x;
  if (b >= B_) return;
  #pragma unroll
  for (int k = 0; k < 2; ++k) {
    int e = topi[b * 2 + k];
    int pos = atomicAdd(&cursors[e], 1);
    int slot = offsets[e] + pos;
    atok[slot] = b;
    slot_of[b * 2 + k] = slot;
  }
}

__global__ __launch_bounds__(256) void k_gather(const float* __restrict__ x,
                                                const int* __restrict__ atok,
                                                u16* __restrict__ Xg) {
  int slot = blockIdx.x;
  int tok = atok[slot];
  int c = threadIdx.x * 4;
  float4 v = *(const float4*)&x[(size_t)tok * D_ + c];
  const float* vf = reinterpret_cast<const float*>(&v);
  u16x4 o;
  o.x = f2h_bits(vf[0]); o.y = f2h_bits(vf[1]);
  o.z = f2h_bits(vf[2]); o.w = f2h_bits(vf[3]);
  *(u16x4*)&Xg[(size_t)slot * D_ + c] = o;
}

// convert + transpose v2: src [E][K][N] fp32 -> dst [E][N][K] f16.
// 64x64 tiles; LDS staged as [n][k] (pad 72 -> 144B rows, 16B-aligned);
// global stores are coalesced u16x8 (16B).
__global__ __launch_bounds__(256) void k_cvt_t(const float* __restrict__ src,
                                               u16* __restrict__ dst, int K, int N) {
  const int e = blockIdx.z;
  const int kt = blockIdx.x * 64;
  const int nt = blockIdx.y * 64;
  __shared__ __align__(16) u16 t[64][72];     // [n][k]
  const float* s = src + (size_t)e * K * N;
  u16* d = dst + (size_t)e * N * K;
  const int nq = threadIdx.x & 15;            // float4 index across n
  const int kr = threadIdx.x >> 4;            // 0..15
  #pragma unroll
  for (int i = 0; i < 4; ++i) {
    int k = kr + i * 16;
    float4 v = *(const float4*)&s[(size_t)(kt + k) * N + nt + nq * 4];
    t[nq*4+0][k] = f2h_bits(v.x); t[nq*4+1][k] = f2h_bits(v.y);
    t[nq*4+2][k] = f2h_bits(v.z); t[nq*4+3][k] = f2h_bits(v.w);
  }
  __syncthreads();
  const int n = threadIdx.x >> 2;             // 0..63
  const int kq = threadIdx.x & 3;             // 0..3 (16 u16 each)
  u16x8 a = *(const u16x8*)&t[n][kq * 16];
  u16x8 b = *(const u16x8*)&t[n][kq * 16 + 8];
  u16* dp = &d[(size_t)(nt + n) * K + kt + kq * 16];
  *(u16x8*)(dp) = a;
  *(u16x8*)(dp + 8) = b;
}

#define GLDS(g, l) __builtin_amdgcn_global_load_lds( \
    (const u32 __attribute__((address_space(1)))*)(g), \
    (u32 __attribute__((address_space(3)))*)(l), 16, 0, 0)

#define VMWAIT(N) asm volatile("s_waitcnt vmcnt(" #N ")" ::: "memory")
#define BARRIER() do { __builtin_amdgcn_s_barrier(); \
                       asm volatile("" ::: "memory"); } while (0)

// ==== 128(M)x256(N) tile, BK=32, RING-3 LDS (72KB), 8 waves (R15-proven) ====
#define NXT(x) ((x) == 24576 ? 0 : (x) + 12288)

#define STG3(LDK, kt, sb) do { \
  const int r_ = lane >> 2; \
  const int sc_ = ((lane & 3) ^ ((r_ ^ (r_ >> 2)) & 3)) * 8; \
  { \
    int rw = wid * 16 + r_; \
    GLDS(Ap + (size_t)rw * (LDK) + (kt) * 32 + sc_, SM + (sb) + wid * 512); \
  } \
  _Pragma("unroll") \
  for (int j = 0; j < 2; ++j) { \
    int seg = wid * 2 + j; \
    GLDS(Bp + (size_t)(seg * 16 + r_) * (LDK) + (kt) * 32 + sc_, \
         SM + (sb) + 4096 + seg * 512); \
  } } while (0)

#define RD_FR(rb_) do { \
  const int r15_ = lane & 15; \
  const int co_ = (((lane >> 4) ^ ((r15_ ^ (r15_ >> 2)) & 3)) * 8); \
  _Pragma("unroll") \
  for (int mi = 0; mi < 4; ++mi) \
    af[mi] = *(const f16x8*)&SM[(rb_) + (wr * 64 + mi * 16 + r15_) * 32 + co_]; \
  _Pragma("unroll") \
  for (int n = 0; n < 4; ++n) \
    bf[n] = *(const f16x8*)&SM[(rb_) + 4096 + (wc * 64 + n * 16 + r15_) * 32 + co_]; \
} while (0)

#define MM16() do { \
  __builtin_amdgcn_s_setprio(1); \
  _Pragma("unroll") \
  for (int mi = 0; mi < 4; ++mi) \
    _Pragma("unroll") \
    for (int n = 0; n < 4; ++n) \
      acc[mi][n] = __builtin_amdgcn_mfma_f32_16x16x32_f16(af[mi], bf[n], acc[mi][n], 0, 0, 0); \
  __builtin_amdgcn_s_setprio(0); \
} while (0)

#define KLOOP(LDK, NT) do { \
  int rb = 0, wb = 24576; \
  STG3(LDK, 0, 0); \
  STG3(LDK, 1, 12288); \
  VMWAIT(3); \
  BARRIER(); \
  for (int t = 0; t < (NT); ++t) { \
    RD_FR(rb); \
    if (t + 2 < (NT)) STG3(LDK, t + 2, wb); \
    BARRIER(); \
    MM16(); \
    if (t + 2 < (NT)) VMWAIT(3); \
    else if (t + 1 < (NT)) VMWAIT(0); \
    BARRIER(); \
    rb = NXT(rb); wb = NXT(wb); \
  } \
} while (0)

// GEMM1: Hb[row][n] = gelu( Xg[row][:] @ W1t[e][n][:]^T + b1[e][n] )  (f16)
// DENSE grid 2176 = 8 XCD x 17 mtile-groups x 16 ntiles; bijective XCD-grouped
// decode: all 16 ntiles of one mtile share blockIdx mod 8 -> same XCD L2.
__global__ __launch_bounds__(512, 4) void k_gemm1(
    const u16* __restrict__ Xg, const u16* __restrict__ W1t,
    const float* __restrict__ b1, const int* __restrict__ offsets,
    u16* __restrict__ Hb) {
  const int L = blockIdx.x;
  const int xcd = L & 7;
  const int s = L >> 3;                       // 0..271
  const int nt = s & 15;
  const int mtile = ((s >> 4) << 3) | xcd;    // 0..135, bijective (136 = 8*17)
  const int row0 = mtile * 128;
  if (row0 >= offsets[E_]) return;
  int e = 0;
  #pragma unroll
  for (int i = 1; i < E_; ++i) e = (row0 >= offsets[i]) ? i : e;
  const int n0 = nt * 256;
  const int tid = threadIdx.x, lane = tid & 63, wid = tid >> 6;
  const int wr = wid >> 2, wc = wid & 3;    // 2M x 4N waves, wave-tile 64x64
  __shared__ __align__(16) u16 SM[36864];   // 72 KB ring-3
  f32x4 acc[4][4] = {};
  f16x8 af[4], bf[4];
  const u16* Ap = Xg + (size_t)row0 * D_;
  const u16* Bp = W1t + (size_t)e * H_ * D_ + (size_t)n0 * D_;

  KLOOP(D_, 32);

  // epilogue: bias+gelu -> LDS (64 x 264 u16, 528B rows) -> 16B stores
  const int rhi = (lane >> 4) * 4, cix = lane & 15;
  float bv[4];
  #pragma unroll
  for (int n = 0; n < 4; ++n) bv[n] = b1[e * H_ + n0 + wc * 64 + n * 16 + cix];
  #pragma unroll
  for (int r = 0; r < 2; ++r) {
    if (wr == r) {
      #pragma unroll
      for (int m = 0; m < 4; ++m)
        #pragma unroll
        for (int n = 0; n < 4; ++n)
          #pragma unroll
          for (int j = 0; j < 4; ++j)
            SM[(m * 16 + rhi + j) * 264 + wc * 64 + n * 16 + cix] =
                f2h_bits(gelu_f(acc[m][n][j] + bv[n]));
    }
    __syncthreads();
    {
      const int rl = tid >> 3, co = (tid & 7) * 32;
      u16* dst = &Hb[(size_t)(row0 + r * 64 + rl) * H_ + n0 + co];
      const u16* srcp = &SM[rl * 264 + co];
      #pragma unroll
      for (int qq = 0; qq < 4; ++qq)
        *(u16x8*)(dst + qq * 8) = *(const u16x8*)(srcp + qq * 8);
    }
    __syncthreads();
  }
}

// GEMM2: Y[row][n] = Hb[row][:] @ W2t[e][n][:]^T + b2[e][n]   (f16, NO atomics)
// DENSE grid 544 = 8 XCD x 17 mtile-groups x 4 ntiles, XCD-grouped; full K.
__global__ __launch_bounds__(512, 4) void k_gemm2(
    const u16* __restrict__ Hb, const u16* __restrict__ W2t,
    const float* __restrict__ b2, const int* __restrict__ offsets,
    u16* __restrict__ Y) {
  const int L = blockIdx.x;
  const int xcd = L & 7;
  const int s = L >> 3;                       // 0..67
  const int nt = s & 3;
  const int mtile = ((s >> 2) << 3) | xcd;    // 0..135, bijective
  const int row0 = mtile * 128;
  if (row0 >= offsets[E_]) return;
  int e = 0;
  #pragma unroll
  for (int i = 1; i < E_; ++i) e = (row0 >= offsets[i]) ? i : e;
  const int n0 = nt * 256;
  const int tid = threadIdx.x, lane = tid & 63, wid = tid >> 6;
  const int wr = wid >> 2, wc = wid & 3;
  __shared__ __align__(16) u16 SM[36864];
  f32x4 acc[4][4] = {};
  f16x8 af[4], bf[4];
  const u16* Ap = Hb + (size_t)row0 * H_;
  const u16* Bp = W2t + (size_t)e * DOUT_ * H_ + (size_t)n0 * H_;

  KLOOP(H_, 128);

  // epilogue: +b2 -> LDS transpose -> coalesced 16B stores into Y (f16)
  const int rhi = (lane >> 4) * 4, cix = lane & 15;
  float bv[4];
  #pragma unroll
  for (int n = 0; n < 4; ++n) bv[n] = b2[e * DOUT_ + n0 + wc * 64 + n * 16 + cix];
  #pragma unroll
  for (int r = 0; r < 2; ++r) {
    if (wr == r) {
      #pragma unroll
      for (int m = 0; m < 4; ++m)
        #pragma unroll
        for (int n = 0; n < 4; ++n)
          #pragma unroll
          for (int j = 0; j < 4; ++j)
            SM[(m * 16 + rhi + j) * 264 + wc * 64 + n * 16 + cix] =
                f2h_bits(acc[m][n][j] + bv[n]);
    }
    __syncthreads();
    {
      const int rl = tid >> 3, co = (tid & 7) * 32;
      u16* dst = &Y[(size_t)(row0 + r * 64 + rl) * DOUT_ + n0 + co];
      const u16* srcp = &SM[rl * 264 + co];
      #pragma unroll
      for (int qq = 0; qq < 4; ++qq)
        *(u16x8*)(dst + qq * 8) = *(const u16x8*)(srcp + qq * 8);
    }
    __syncthreads();
  }
}

// combine: out[b][:] = w0 * Y[s0][:] + w1 * Y[s1][:]
__global__ __launch_bounds__(256) void k_combine(
    const u16* __restrict__ Y, const float* __restrict__ topw,
    const int* __restrict__ slot_of, float* __restrict__ out) {
  const int b = blockIdx.x;
  const int c = threadIdx.x * 4;
  const int s0 = slot_of[b * 2], s1 = slot_of[b * 2 + 1];
  const float w0 = topw[b * 2], w1 = topw[b * 2 + 1];
  u16x4 y0 = *(const u16x4*)&Y[(size_t)s0 * DOUT_ + c];
  u16x4 y1 = *(const u16x4*)&Y[(size_t)s1 * DOUT_ + c];
  float4 o;
  o.x = w0 * h2f(y0.x) + w1 * h2f(y1.x);
  o.y = w0 * h2f(y0.y) + w1 * h2f(y1.y);
  o.z = w0 * h2f(y0.z) + w1 * h2f(y1.z);
  o.w = w0 * h2f(y0.w) + w1 * h2f(y1.w);
  *(float4*)&out[(size_t)b * DOUT_ + c] = o;
}

extern "C" void kernel_launch(void* const* d_in, const int* in_sizes, int n_in,
                              void* d_out, int out_size, void* d_ws, size_t ws_size,
                              hipStream_t stream) {
  const float* x  = (const float*)d_in[0];
  const float* Wg = (const float*)d_in[1];
  const float* bg = (const float*)d_in[2];
  const float* W1 = (const float*)d_in[3];
  const float* b1 = (const float*)d_in[4];
  const float* W2 = (const float*)d_in[5];
  const float* b2 = (const float*)d_in[6];
  float* out = (float*)d_out;

  char* ws = (char*)d_ws;
  int*   counts  = (int*)(ws + 0);
  int*   cursors = (int*)(ws + 32);
  int*   offsets = (int*)(ws + 64);
  float* usage   = (float*)(ws + 128);
  int*   topi    = (int*)(ws + OFF_TOPI);
  float* topw    = (float*)(ws + OFF_TOPW);
  int*   atok    = (int*)(ws + OFF_ATOK);
  int*   slot_of = (int*)(ws + OFF_SLOT);
  u16*   Xg      = (u16*)(ws + OFF_XG);
  u16*   W1t     = (u16*)(ws + OFF_W1T);
  u16*   W2t     = (u16*)(ws + OFF_W2T);
  u16*   Y       = (u16*)(ws + OFF_Y);
  u16*   Hb      = (u16*)(ws + OFF_HB);

  k_init<<<(MAXR + 255) / 256, 256, 0, stream>>>(atok, (int*)ws);
  k_gate<<<B_ / 4, 256, 0, stream>>>(x, Wg, bg, counts, usage, topi, topw);
  k_scan_aux<<<1, 64, 0, stream>>>(counts, offsets, usage, out + (size_t)B_ * DOUT_);
  k_scatter<<<B_ / 256, 256, 0, stream>>>(topi, offsets, cursors, atok, slot_of);
  k_gather<<<MAXR, 256, 0, stream>>>(x, atok, Xg);
  k_cvt_t<<<dim3(D_ / 64, H_ / 64, E_), 256, 0, stream>>>(W1, W1t, D_, H_);
  k_gemm1<<<(MAXR / 128) * 16, 512, 0, stream>>>(Xg, W1t, b1, offsets, Hb);
  k_cvt_t<<<dim3(H_ / 64, DOUT_ / 64, E_), 256, 0, stream>>>(W2, W2t, H_, DOUT_);
  k_gemm2<<<(MAXR / 128) * 4, 512, 0, stream>>>(Hb, W2t, b2, offsets, Y);
  k_combine<<<B_, 256, 0, stream>>>(Y, topw, slot_of, out);
}

// Round 18
// 793.871 us; speedup vs baseline: 1.0294x; 1.0294x over previous
//
#include <hip/hip_runtime.h>
#include <hip/hip_bf16.h>
#include <hip/hip_fp16.h>

#define B_    8192
#define D_    1024
#define H_    4096
#define DOUT_ 1024
#define E_    8
#define MAXR  17408   // 16384 assignments + 8*128 padding

typedef float    f32x4 __attribute__((ext_vector_type(4)));
typedef _Float16 f16x8 __attribute__((ext_vector_type(8)));
typedef unsigned short u16;
typedef u16      u16x8 __attribute__((ext_vector_type(8)));
typedef u16      u16x4 __attribute__((ext_vector_type(4)));
typedef unsigned int u32;

__device__ __forceinline__ u16 f2h_bits(float f) {
  _Float16 h = (_Float16)f;
  return __builtin_bit_cast(u16, h);
}
__device__ __forceinline__ float h2f(u16 b) {
  return (float)__builtin_bit_cast(_Float16, b);
}

// tanh-form gelu (max abs err vs erf-gelu ~3e-4; threshold margin 4x)
__device__ __forceinline__ float gelu_f(float v) {
  float z = 0.7978845608028654f * (v + 0.044715f * v * v * v);
  float ez = __expf(2.f * z);
  float th = 1.f - 2.f / (ez + 1.f);
  return 0.5f * v * (1.f + th);
}

// ---- workspace layout (bytes) ----
#define OFF_TOPI 512                       // int[16384]
#define OFF_TOPW (OFF_TOPI + 65536)        // float[16384]
#define OFF_ATOK (OFF_TOPW + 65536)        // int[17408]
#define OFF_SLOT (OFF_ATOK + 69632)        // int[16384] slot_of
#define OFF_XG   524288                    // u16[17408*1024] f16 (dead after gemm1)
#define OFF_W1T  (OFF_XG + 35651584)       // u16[8*4096*1024] f16 (dead after gemm1)
#define OFF_W2T  OFF_XG                    // u16[8*1024*4096], ALIASES Xg (built after gemm1)
#define OFF_Y    (OFF_XG + 67108864)       // u16[17408*1024], ALIASES W1T tail (after gemm1)
#define OFF_HB   (OFF_W1T + 67108864)      // u16[17408*4096] f16
// end = 245,891,072 bytes

__global__ void k_init(int* __restrict__ atok, int* __restrict__ meta) {
  int i = blockIdx.x * 256 + threadIdx.x;
  if (i < MAXR) atok[i] = 0;
  if (blockIdx.x == 0 && threadIdx.x < 64) meta[threadIdx.x] = 0;
}

__global__ __launch_bounds__(256) void k_gate(
    const float* __restrict__ x, const float* __restrict__ Wg,
    const float* __restrict__ bg, int* __restrict__ counts,
    float* __restrict__ usage, int* __restrict__ topi, float* __restrict__ topw) {
  __shared__ float su[E_];
  if (threadIdx.x < E_) su[threadIdx.x] = 0.f;
  __syncthreads();
  const int lane = threadIdx.x & 63;
  const int b = blockIdx.x * 4 + (threadIdx.x >> 6);
  float p[E_] = {0.f,0.f,0.f,0.f,0.f,0.f,0.f,0.f};
  #pragma unroll
  for (int j = 0; j < 4; ++j) {
    int d = j * 256 + lane * 4;
    float4 xv = *(const float4*)&x[(size_t)b * D_ + d];
    const float* wr = &Wg[(size_t)d * E_];
    #pragma unroll
    for (int c = 0; c < 4; ++c) {
      float xc = reinterpret_cast<const float*>(&xv)[c];
      #pragma unroll
      for (int e = 0; e < E_; ++e) p[e] += xc * wr[c * E_ + e];
    }
  }
  #pragma unroll
  for (int off = 32; off >= 1; off >>= 1)
    #pragma unroll
    for (int e = 0; e < E_; ++e) p[e] += __shfl_xor(p[e], off, 64);
  float mx = -1e30f;
  #pragma unroll
  for (int e = 0; e < E_; ++e) { p[e] += bg[e]; mx = fmaxf(mx, p[e]); }
  int i0 = 0; float l0 = p[0];
  #pragma unroll
  for (int e = 1; e < E_; ++e) if (p[e] > l0) { l0 = p[e]; i0 = e; }
  int i1 = -1; float l1 = -1e30f;
  #pragma unroll
  for (int e = 0; e < E_; ++e) if (e != i0 && p[e] > l1) { l1 = p[e]; i1 = e; }
  float s = 0.f;
  #pragma unroll
  for (int e = 0; e < E_; ++e) { p[e] = expf(p[e] - mx); s += p[e]; }
  float inv = 1.f / s;
  if (lane == 0) {
    float e0 = expf(l0 - mx), e1 = expf(l1 - mx);
    float wsum = e0 + e1;
    topi[b * 2] = i0; topi[b * 2 + 1] = i1;
    topw[b * 2] = e0 / wsum; topw[b * 2 + 1] = e1 / wsum;
    atomicAdd(&counts[i0], 1);
    atomicAdd(&counts[i1], 1);
    #pragma unroll
    for (int e = 0; e < E_; ++e) atomicAdd(&su[e], p[e] * inv);
  }
  __syncthreads();
  if (threadIdx.x < E_) atomicAdd(&usage[threadIdx.x], su[threadIdx.x]);
}

__global__ void k_scan_aux(const int* __restrict__ counts, int* __restrict__ offsets,
                           const float* __restrict__ usage, float* __restrict__ auxp) {
  if (threadIdx.x == 0) {
    int off = 0;
    for (int e = 0; e < E_; ++e) { offsets[e] = off; off += (counts[e] + 127) & ~127; }
    offsets[E_] = off;
    float aux = 0.f;
    const float lu = logf(1.0f / (float)E_);
    for (int e = 0; e < E_; ++e) {
      float u = usage[e] * (1.0f / (float)B_);
      aux += u * lu - logf(u) * (1.0f / (float)E_);
    }
    *auxp = aux;
  }
}

__global__ void k_scatter(const int* __restrict__ topi, const int* __restrict__ offsets,
                          int* __restrict__ cursors, int* __restrict__ atok,
                          int* __restrict__ slot_of) {
  int b = blockIdx.x * 256 + threadIdx.x;
  if (b >= B_) return;
  #pragma unroll
  for (int k = 0; k < 2; ++k) {
    int e = topi[b * 2 + k];
    int pos = atomicAdd(&cursors[e], 1);
    int slot = offsets[e] + pos;
    atok[slot] = b;
    slot_of[b * 2 + k] = slot;
  }
}

__global__ __launch_bounds__(256) void k_gather(const float* __restrict__ x,
                                                const int* __restrict__ atok,
                                                u16* __restrict__ Xg) {
  int slot = blockIdx.x;
  int tok = atok[slot];
  int c = threadIdx.x * 4;
  float4 v = *(const float4*)&x[(size_t)tok * D_ + c];
  const float* vf = reinterpret_cast<const float*>(&v);
  u16x4 o;
  o.x = f2h_bits(vf[0]); o.y = f2h_bits(vf[1]);
  o.z = f2h_bits(vf[2]); o.w = f2h_bits(vf[3]);
  *(u16x4*)&Xg[(size_t)slot * D_ + c] = o;
}

// convert + transpose v2: src [E][K][N] fp32 -> dst [E][N][K] f16.
// 64x64 tiles; LDS staged as [n][k] (pad 72, 16B-aligned rows);
// global stores are coalesced u16x8 (16B).
__global__ __launch_bounds__(256) void k_cvt_t(const float* __restrict__ src,
                                               u16* __restrict__ dst, int K, int N) {
  const int e = blockIdx.z;
  const int kt = blockIdx.x * 64;
  const int nt = blockIdx.y * 64;
  __shared__ __align__(16) u16 t[64][72];     // [n][k]
  const float* s = src + (size_t)e * K * N;
  u16* d = dst + (size_t)e * N * K;
  const int nq = threadIdx.x & 15;
  const int kr = threadIdx.x >> 4;
  #pragma unroll
  for (int i = 0; i < 4; ++i) {
    int k = kr + i * 16;
    float4 v = *(const float4*)&s[(size_t)(kt + k) * N + nt + nq * 4];
    t[nq*4+0][k] = f2h_bits(v.x); t[nq*4+1][k] = f2h_bits(v.y);
    t[nq*4+2][k] = f2h_bits(v.z); t[nq*4+3][k] = f2h_bits(v.w);
  }
  __syncthreads();
  const int n = threadIdx.x >> 2;
  const int kq = threadIdx.x & 3;
  u16x8 a = *(const u16x8*)&t[n][kq * 16];
  u16x8 b = *(const u16x8*)&t[n][kq * 16 + 8];
  u16* dp = &d[(size_t)(nt + n) * K + kt + kq * 16];
  *(u16x8*)(dp) = a;
  *(u16x8*)(dp + 8) = b;
}

#define GLDS(g, l) __builtin_amdgcn_global_load_lds( \
    (const u32 __attribute__((address_space(1)))*)(g), \
    (u32 __attribute__((address_space(3)))*)(l), 16, 0, 0)

#define VMWAIT(N) asm volatile("s_waitcnt vmcnt(" #N ")" ::: "memory")
#define BARRIER() do { __builtin_amdgcn_s_barrier(); \
                       asm volatile("" ::: "memory"); } while (0)

// ==== 128(M)x256(N) tile, BK=32, RING-3 LDS (72KB), 8 waves (R15-proven) ====
// SINGLE barrier per phase (ledger: tile-t readiness AND the WAR guard on
// b_{t-1} are both established by the previous phase's VMWAIT(3)+barrier —
// reads of b_{t-1} were consumed by that phase's MFMA before its barrier).
#define NXT(x) ((x) == 24576 ? 0 : (x) + 12288)

#define STG3(LDK, kt, sb) do { \
  const int r_ = lane >> 2; \
  const int sc_ = ((lane & 3) ^ ((r_ ^ (r_ >> 2)) & 3)) * 8; \
  { \
    int rw = wid * 16 + r_; \
    GLDS(Ap + (size_t)rw * (LDK) + (kt) * 32 + sc_, SM + (sb) + wid * 512); \
  } \
  _Pragma("unroll") \
  for (int j = 0; j < 2; ++j) { \
    int seg = wid * 2 + j; \
    GLDS(Bp + (size_t)(seg * 16 + r_) * (LDK) + (kt) * 32 + sc_, \
         SM + (sb) + 4096 + seg * 512); \
  } } while (0)

#define RD_FR(rb_) do { \
  const int r15_ = lane & 15; \
  const int co_ = (((lane >> 4) ^ ((r15_ ^ (r15_ >> 2)) & 3)) * 8); \
  _Pragma("unroll") \
  for (int mi = 0; mi < 4; ++mi) \
    af[mi] = *(const f16x8*)&SM[(rb_) + (wr * 64 + mi * 16 + r15_) * 32 + co_]; \
  _Pragma("unroll") \
  for (int n = 0; n < 4; ++n) \
    bf[n] = *(const f16x8*)&SM[(rb_) + 4096 + (wc * 64 + n * 16 + r15_) * 32 + co_]; \
} while (0)

#define MM16() do { \
  __builtin_amdgcn_s_setprio(1); \
  _Pragma("unroll") \
  for (int mi = 0; mi < 4; ++mi) \
    _Pragma("unroll") \
    for (int n = 0; n < 4; ++n) \
      acc[mi][n] = __builtin_amdgcn_mfma_f32_16x16x32_f16(af[mi], bf[n], acc[mi][n], 0, 0, 0); \
  __builtin_amdgcn_s_setprio(0); \
} while (0)

// Ring-3, ONE barrier per phase:
// {RD(t); STG(t+2); MFMA(t); VMWAIT(3) [drain t+1, keep t+2]; barrier}
#define KLOOP(LDK, NT) do { \
  int rb = 0, wb = 24576; \
  STG3(LDK, 0, 0); \
  STG3(LDK, 1, 12288); \
  VMWAIT(3); \
  BARRIER(); \
  for (int t = 0; t < (NT); ++t) { \
    RD_FR(rb); \
    if (t + 2 < (NT)) STG3(LDK, t + 2, wb); \
    MM16(); \
    if (t + 2 < (NT)) VMWAIT(3); \
    else if (t + 1 < (NT)) VMWAIT(0); \
    BARRIER(); \
    rb = NXT(rb); wb = NXT(wb); \
  } \
} while (0)

// GEMM1: Hb[row][n] = gelu( Xg[row][:] @ W1t[e][n][:]^T + b1[e][n] )  (f16)
// DENSE mt-major grid (R16-proven best FETCH): 136 mtiles x 16 ntiles.
__global__ __launch_bounds__(512, 4) void k_gemm1(
    const u16* __restrict__ Xg, const u16* __restrict__ W1t,
    const float* __restrict__ b1, const int* __restrict__ offsets,
    u16* __restrict__ Hb) {
  const int L = blockIdx.x;
  const int mtile = L >> 4;
  const int nt = L & 15;
  const int row0 = mtile * 128;
  if (row0 >= offsets[E_]) return;
  int e = 0;
  #pragma unroll
  for (int i = 1; i < E_; ++i) e = (row0 >= offsets[i]) ? i : e;
  const int n0 = nt * 256;
  const int tid = threadIdx.x, lane = tid & 63, wid = tid >> 6;
  const int wr = wid >> 2, wc = wid & 3;    // 2M x 4N waves, wave-tile 64x64
  __shared__ __align__(16) u16 SM[36864];   // 72 KB ring-3
  f32x4 acc[4][4] = {};
  f16x8 af[4], bf[4];
  const u16* Ap = Xg + (size_t)row0 * D_;
  const u16* Bp = W1t + (size_t)e * H_ * D_ + (size_t)n0 * D_;

  KLOOP(D_, 32);

  // epilogue: bias+gelu -> LDS (64 x 264 u16, 528B rows) -> 16B stores
  const int rhi = (lane >> 4) * 4, cix = lane & 15;
  float bv[4];
  #pragma unroll
  for (int n = 0; n < 4; ++n) bv[n] = b1[e * H_ + n0 + wc * 64 + n * 16 + cix];
  #pragma unroll
  for (int r = 0; r < 2; ++r) {
    if (wr == r) {
      #pragma unroll
      for (int m = 0; m < 4; ++m)
        #pragma unroll
        for (int n = 0; n < 4; ++n)
          #pragma unroll
          for (int j = 0; j < 4; ++j)
            SM[(m * 16 + rhi + j) * 264 + wc * 64 + n * 16 + cix] =
                f2h_bits(gelu_f(acc[m][n][j] + bv[n]));
    }
    __syncthreads();
    {
      const int rl = tid >> 3, co = (tid & 7) * 32;
      u16* dst = &Hb[(size_t)(row0 + r * 64 + rl) * H_ + n0 + co];
      const u16* srcp = &SM[rl * 264 + co];
      #pragma unroll
      for (int qq = 0; qq < 4; ++qq)
        *(u16x8*)(dst + qq * 8) = *(const u16x8*)(srcp + qq * 8);
    }
    __syncthreads();
  }
}

// GEMM2: Y[row][n] = Hb[row][:] @ W2t[e][n][:]^T + b2[e][n]   (f16, NO atomics)
// DENSE mt-major grid: 136 mtiles x 4 ntiles; full K=4096 (NT=128).
__global__ __launch_bounds__(512, 4) void k_gemm2(
    const u16* __restrict__ Hb, const u16* __restrict__ W2t,
    const float* __restrict__ b2, const int* __restrict__ offsets,
    u16* __restrict__ Y) {
  const int L = blockIdx.x;
  const int mtile = L >> 2;
  const int nt = L & 3;
  const int row0 = mtile * 128;
  if (row0 >= offsets[E_]) return;
  int e = 0;
  #pragma unroll
  for (int i = 1; i < E_; ++i) e = (row0 >= offsets[i]) ? i : e;
  const int n0 = nt * 256;
  const int tid = threadIdx.x, lane = tid & 63, wid = tid >> 6;
  const int wr = wid >> 2, wc = wid & 3;
  __shared__ __align__(16) u16 SM[36864];
  f32x4 acc[4][4] = {};
  f16x8 af[4], bf[4];
  const u16* Ap = Hb + (size_t)row0 * H_;
  const u16* Bp = W2t + (size_t)e * DOUT_ * H_ + (size_t)n0 * H_;

  KLOOP(H_, 128);

  // epilogue: +b2 -> LDS transpose -> coalesced 16B stores into Y (f16)
  const int rhi = (lane >> 4) * 4, cix = lane & 15;
  float bv[4];
  #pragma unroll
  for (int n = 0; n < 4; ++n) bv[n] = b2[e * DOUT_ + n0 + wc * 64 + n * 16 + cix];
  #pragma unroll
  for (int r = 0; r < 2; ++r) {
    if (wr == r) {
      #pragma unroll
      for (int m = 0; m < 4; ++m)
        #pragma unroll
        for (int n = 0; n < 4; ++n)
          #pragma unroll
          for (int j = 0; j < 4; ++j)
            SM[(m * 16 + rhi + j) * 264 + wc * 64 + n * 16 + cix] =
                f2h_bits(acc[m][n][j] + bv[n]);
    }
    __syncthreads();
    {
      const int rl = tid >> 3, co = (tid & 7) * 32;
      u16* dst = &Y[(size_t)(row0 + r * 64 + rl) * DOUT_ + n0 + co];
      const u16* srcp = &SM[rl * 264 + co];
      #pragma unroll
      for (int qq = 0; qq < 4; ++qq)
        *(u16x8*)(dst + qq * 8) = *(const u16x8*)(srcp + qq * 8);
    }
    __syncthreads();
  }
}

// combine: out[b][:] = w0 * Y[s0][:] + w1 * Y[s1][:]
__global__ __launch_bounds__(256) void k_combine(
    const u16* __restrict__ Y, const float* __restrict__ topw,
    const int* __restrict__ slot_of, float* __restrict__ out) {
  const int b = blockIdx.x;
  const int c = threadIdx.x * 4;
  const int s0 = slot_of[b * 2], s1 = slot_of[b * 2 + 1];
  const float w0 = topw[b * 2], w1 = topw[b * 2 + 1];
  u16x4 y0 = *(const u16x4*)&Y[(size_t)s0 * DOUT_ + c];
  u16x4 y1 = *(const u16x4*)&Y[(size_t)s1 * DOUT_ + c];
  float4 o;
  o.x = w0 * h2f(y0.x) + w1 * h2f(y1.x);
  o.y = w0 * h2f(y0.y) + w1 * h2f(y1.y);
  o.z = w0 * h2f(y0.z) + w1 * h2f(y1.z);
  o.w = w0 * h2f(y0.w) + w1 * h2f(y1.w);
  *(float4*)&out[(size_t)b * DOUT_ + c] = o;
}

extern "C" void kernel_launch(void* const* d_in, const int* in_sizes, int n_in,
                              void* d_out, int out_size, void* d_ws, size_t ws_size,
                              hipStream_t stream) {
  const float* x  = (const float*)d_in[0];
  const float* Wg = (const float*)d_in[1];
  const float* bg = (const float*)d_in[2];
  const float* W1 = (const float*)d_in[3];
  const float* b1 = (const float*)d_in[4];
  const float* W2 = (const float*)d_in[5];
  const float* b2 = (const float*)d_in[6];
  float* out = (float*)d_out;

  char* ws = (char*)d_ws;
  int*   counts  = (int*)(ws + 0);
  int*   cursors = (int*)(ws + 32);
  int*   offsets = (int*)(ws + 64);
  float* usage   = (float*)(ws + 128);
  int*   topi    = (int*)(ws + OFF_TOPI);
  float* topw    = (float*)(ws + OFF_TOPW);
  int*   atok    = (int*)(ws + OFF_ATOK);
  int*   slot_of = (int*)(ws + OFF_SLOT);
  u16*   Xg      = (u16*)(ws + OFF_XG);
  u16*   W1t     = (u16*)(ws + OFF_W1T);
  u16*   W2t     = (u16*)(ws + OFF_W2T);
  u16*   Y       = (u16*)(ws + OFF_Y);
  u16*   Hb      = (u16*)(ws + OFF_HB);

  k_init<<<(MAXR + 255) / 256, 256, 0, stream>>>(atok, (int*)ws);
  k_gate<<<B_ / 4, 256, 0, stream>>>(x, Wg, bg, counts, usage, topi, topw);
  k_scan_aux<<<1, 64, 0, stream>>>(counts, offsets, usage, out + (size_t)B_ * DOUT_);
  k_scatter<<<B_ / 256, 256, 0, stream>>>(topi, offsets, cursors, atok, slot_of);
  k_gather<<<MAXR, 256, 0, stream>>>(x, atok, Xg);
  k_cvt_t<<<dim3(D_ / 64, H_ / 64, E_), 256, 0, stream>>>(W1, W1t, D_, H_);
  k_gemm1<<<(MAXR / 128) * 16, 512, 0, stream>>>(Xg, W1t, b1, offsets, Hb);
  k_cvt_t<<<dim3(H_ / 64, DOUT_ / 64, E_), 256, 0, stream>>>(W2, W2t, H_, DOUT_);
  k_gemm2<<<(MAXR / 128) * 4, 512, 0, stream>>>(Hb, W2t, b2, offsets, Y);
  k_combine<<<B_, 256, 0, stream>>>(Y, topw, slot_of, out);
}